// Round 12
// baseline (104.512 us; speedup 1.0000x reference)
//
#include <hip/hip_runtime.h>

// Problem constants (B=8, V=8192, N=2048, C=128)
#define BB 8
#define VV 8192
#define NN 2048
#define CC 128
#define SEL_LD 34   // 32-row selT tile leading dim (even -> 8B-aligned float2 reads)

// Shared memory (~49 KB -> 3 blocks/CU, 24 waves/CU):
//   pts[2048] float4        : 32 KB   (argmin blocks only)
//   union {
//     selT[128*34] float    : 17 KB   (MLP blocks)
//     { sd, si }            : 12 KB   (argmin merge scratch: 8 chunks x 256)
//   }
struct MergeScratch {
    float sd[8 * 256];
    unsigned short si[8 * 256];
};
union SelOrMerge {
    float selT[CC * SEL_LD];
    MergeScratch m;
};

// K1, 768 blocks x 512 thr, block-specialized:
//   blocks [0,256)   : argmin for 256 vertices each -> idx_out (u16)
//   blocks [256,768) : MLP for 32 rows each         -> mlp_out
// __launch_bounds__(512, 6): LDS caps us at 3 blocks/CU = 6 waves/EU anyway,
// so give the register allocator the full ~85-VGPR budget -> unrolled loads
// stay in flight (r10's VGPR_Count=32 strangled the ds_read/W1 pipelining).
// Bit-exact reference rounding (frozen since round 4):
//   sp = (rn(px^2)+rn(py^2))+rn(pz^2)
//   e2 = fma(2vz,pz, fma(2vy,py, rn(2vx*px))) == rn(2e)   (2x exact)
//   d2 = rn(rn(sv - e2) + sp)
//   strict < + ascending chunk merge -> first-index tie-break.
__global__ __launch_bounds__(512, 6) void argmin_mlp_kernel(
    const float* __restrict__ verts, const float* __restrict__ graph_pos,
    const float* __restrict__ processed, const float* __restrict__ W1,
    const float* __restrict__ b1, const float* __restrict__ W2,
    const float* __restrict__ b2, float* __restrict__ mlp_out,
    unsigned short* __restrict__ idx_out)
{
    __shared__ float4 pts[NN];        // 32 KB
    __shared__ SelOrMerge u;          // 17 KB

    const int t = threadIdx.x;
    const int lane = t & 63;
    const int w = __builtin_amdgcn_readfirstlane(t >> 6);   // wave id 0..7

    if (blockIdx.x < 256) {
        // ================= ARGMIN BLOCK =================
        const int bid = blockIdx.x;
        const int b = bid >> 5;           // 32 blocks per batch
        const int v0 = (bid & 31) * 256;

        // stage pts (2048 points of batch b) with exact sp
        #pragma unroll
        for (int i = 0; i < 4; ++i) {
            int p = t + i * 512;
            const float* g3 = graph_pos + ((size_t)b * NN + p) * 3;
            float px = g3[0], py = g3[1], pz = g3[2];
            float sp = __fadd_rn(__fadd_rn(__fmul_rn(px, px), __fmul_rn(py, py)),
                                 __fmul_rn(pz, pz));
            pts[p] = make_float4(px, py, pz, sp);
        }

        // vertex registers (Vt=4 per lane)
        float sv[4], tx[4], ty[4], tz[4];
        #pragma unroll
        for (int j = 0; j < 4; ++j) {
            int v = v0 + j * 64 + lane;
            const float* vp = verts + ((size_t)b * VV + v) * 3;
            float x = vp[0], y = vp[1], z = vp[2];
            sv[j] = __fadd_rn(__fadd_rn(__fmul_rn(x, x), __fmul_rn(y, y)),
                              __fmul_rn(z, z));
            tx[j] = x + x; ty[j] = y + y; tz[j] = z + z;   // exact 2x
        }
        __syncthreads();

        // scan: wave w covers point chunk [w*256, w*256+256)
        // software-pipelined: next Q loaded before current is consumed
        const float4* P = &pts[w * 256];
        float best[4] = {3.4e38f, 3.4e38f, 3.4e38f, 3.4e38f};
        int bi[4] = {0, 0, 0, 0};
        float4 Qc = P[0];
        #pragma unroll 4
        for (int n = 0; n < 256; ++n) {
            float4 Qn = P[(n + 1) & 255];   // ds_read issued ahead of use
            #pragma unroll
            for (int j = 0; j < 4; ++j) {
                float e2 = fmaf(tz[j], Qc.z, fmaf(ty[j], Qc.y, __fmul_rn(tx[j], Qc.x)));
                float d2 = __fadd_rn(__fsub_rn(sv[j], e2), Qc.w);
                if (d2 < best[j]) { best[j] = d2; bi[j] = n; }  // strict <: first idx
            }
            Qc = Qn;
        }

        __syncthreads();   // safe to alias u as merge scratch
        #pragma unroll
        for (int j = 0; j < 4; ++j) {
            u.m.sd[w * 256 + j * 64 + lane] = best[j];
            u.m.si[w * 256 + j * 64 + lane] = (unsigned short)(bi[j] + w * 256);
        }
        __syncthreads();

        if (t < 256) {
            float bb = u.m.sd[t];
            int   ii = u.m.si[t];
            #pragma unroll
            for (int c = 1; c < 8; ++c) {       // ascending chunks: first-index ties
                float d = u.m.sd[c * 256 + t];
                int   i = u.m.si[c * 256 + t];
                if (d < bb) { bb = d; ii = i; }
            }
            idx_out[(size_t)b * VV + v0 + t] = (unsigned short)ii;
        }
    } else {
        // ================= MLP BLOCK (32 rows) =================
        const int mb = blockIdx.x - 256;      // 0..511
        const int row0 = mb * 32;

        #pragma unroll
        for (int i = 0; i < 8; ++i) {
            int flat = i * 512 + t;           // 0..4095
            int r = flat >> 7;                // 0..31
            int k = flat & 127;
            u.selT[k * SEL_LD + r] = processed[(size_t)(row0 + r) * CC + k];
        }
        __syncthreads();

        const int g = t & 31;                 // col group: 4 cols
        const int rb = t >> 5;                // row group: 2 rows, 0..15
        const int c0 = g * 4;
        const int r0 = rb * 2;

        float acc[2][4] = {{0.f, 0.f, 0.f, 0.f}, {0.f, 0.f, 0.f, 0.f}};
        // software-pipelined: W1 row k+1 and selT col k+1 loaded ahead
        float4 wv = *(const float4*)(W1 + c0);
        float2 av = *(const float2*)(&u.selT[r0]);
        #pragma unroll 4
        for (int k = 0; k < CC; ++k) {
            int kn = (k + 1) & 127;
            float4 wvn = *(const float4*)(W1 + kn * CC + c0);
            float2 avn = *(const float2*)(&u.selT[kn * SEL_LD + r0]);
            acc[0][0] = fmaf(av.x, wv.x, acc[0][0]);
            acc[0][1] = fmaf(av.x, wv.y, acc[0][1]);
            acc[0][2] = fmaf(av.x, wv.z, acc[0][2]);
            acc[0][3] = fmaf(av.x, wv.w, acc[0][3]);
            acc[1][0] = fmaf(av.y, wv.x, acc[1][0]);
            acc[1][1] = fmaf(av.y, wv.y, acc[1][1]);
            acc[1][2] = fmaf(av.y, wv.z, acc[1][2]);
            acc[1][3] = fmaf(av.y, wv.w, acc[1][3]);
            wv = wvn; av = avn;
        }

        float4 b1v = *(const float4*)(b1 + c0);
        float4 w2v = *(const float4*)(W2 + c0);
        float bias2 = b2[0];

        #pragma unroll
        for (int i = 0; i < 2; ++i) {
            float h0 = acc[i][0] + b1v.x; h0 = h0 > 0.f ? h0 : 0.f;
            float h1 = acc[i][1] + b1v.y; h1 = h1 > 0.f ? h1 : 0.f;
            float h2 = acc[i][2] + b1v.z; h2 = h2 > 0.f ? h2 : 0.f;
            float h3 = acc[i][3] + b1v.w; h3 = h3 > 0.f ? h3 : 0.f;
            float p = fmaf(h0, w2v.x, fmaf(h1, w2v.y, fmaf(h2, w2v.z, h3 * w2v.w)));
            // reduce across the 32 col-lanes (xor offsets <32 stay in half-wave)
            #pragma unroll
            for (int off = 1; off < 32; off <<= 1) p += __shfl_xor(p, off, 64);
            if (g == 0) mlp_out[row0 + r0 + i] = p + bias2;
        }
    }
}

// K2: out[b,v] = mlp_out[b*NN + idx[b,v]]. mlp_out is 8 KB/batch -> L2 hot.
__global__ __launch_bounds__(256) void gather_kernel(
    const float* __restrict__ mlp_out, const unsigned short* __restrict__ idx,
    float* __restrict__ out)
{
    const int gid = blockIdx.x * 256 + threadIdx.x;   // 0..65535
    const int b = gid >> 13;                          // / VV
    out[gid] = mlp_out[b * NN + (int)idx[gid]];
}

extern "C" void kernel_launch(void* const* d_in, const int* in_sizes, int n_in,
                              void* d_out, int out_size, void* d_ws, size_t ws_size,
                              hipStream_t stream) {
    const float* verts     = (const float*)d_in[0];
    const float* graph_pos = (const float*)d_in[1];
    const float* processed = (const float*)d_in[2];
    const float* W1        = (const float*)d_in[3];
    const float* b1        = (const float*)d_in[4];
    const float* W2        = (const float*)d_in[5];
    const float* b2        = (const float*)d_in[6];
    float* out = (float*)d_out;

    float* mlp_out       = (float*)d_ws;                                 // 64 KB
    unsigned short* idxb = (unsigned short*)((char*)d_ws + BB * NN * 4); // 128 KB

    hipLaunchKernelGGL(argmin_mlp_kernel, dim3(768), dim3(512), 0, stream,
                       verts, graph_pos, processed, W1, b1, W2, b2,
                       mlp_out, idxb);
    hipLaunchKernelGGL(gather_kernel, dim3((BB * VV) / 256), dim3(256), 0, stream,
                       mlp_out, idxb, out);
}

// Round 13
// 102.357 us; speedup vs baseline: 1.0211x; 1.0211x over previous
//
#include <hip/hip_runtime.h>

// Problem constants (B=8, V=8192, N=2048, C=128)
#define BB 8
#define VV 8192
#define NN 2048
#define CC 128
#define SEL_LD 34   // 32-row selT tile leading dim (even -> 8B-aligned float2 reads)

// Shared memory (~49 KB -> 3 blocks/CU, 24 waves/CU):
//   pts[2048] float4        : 32 KB   (argmin blocks only)
//   union {
//     selT[128*34] float    : 17 KB   (MLP blocks)
//     { sd, si }            : 12 KB   (argmin merge scratch: 8 chunks x 256)
//   }
struct MergeScratch {
    float sd[8 * 256];
    unsigned short si[8 * 256];
};
union SelOrMerge {
    float selT[CC * SEL_LD];
    MergeScratch m;
};

// K1, 768 blocks x 512 thr, block-specialized:
//   blocks [0,256)   : argmin for 256 vertices each -> idx_out (u16)
//   blocks [256,768) : MLP for 32 rows each         -> mlp_out
// __launch_bounds__(512, 6): LDS caps occupancy at 3 blocks/CU = 6 waves/EU,
// so raise the VGPR budget to ~85 (vs default-8-wave's 64; r10 measured 32).
// Inner-loop live state at Vt=4 is ~40+ VGPR incl. 4 in-flight float4 Q's —
// at 32 VGPR the unroll-4 ds_reads serialize on lgkmcnt. NO manual SWP (r12
// regressed: address math + Q rotation added ~15% VALU and pinned the order);
// let the compiler pipeline within the bigger budget.
// Bit-exact reference rounding (frozen since round 4):
//   sp = (rn(px^2)+rn(py^2))+rn(pz^2)
//   e2 = fma(2vz,pz, fma(2vy,py, rn(2vx*px))) == rn(2e)   (2x exact)
//   d2 = rn(rn(sv - e2) + sp)
//   strict < + ascending chunk merge -> first-index tie-break.
__global__ __launch_bounds__(512, 6) void argmin_mlp_kernel(
    const float* __restrict__ verts, const float* __restrict__ graph_pos,
    const float* __restrict__ processed, const float* __restrict__ W1,
    const float* __restrict__ b1, const float* __restrict__ W2,
    const float* __restrict__ b2, float* __restrict__ mlp_out,
    unsigned short* __restrict__ idx_out)
{
    __shared__ float4 pts[NN];        // 32 KB
    __shared__ SelOrMerge u;          // 17 KB

    const int t = threadIdx.x;
    const int lane = t & 63;
    const int w = __builtin_amdgcn_readfirstlane(t >> 6);   // wave id 0..7

    if (blockIdx.x < 256) {
        // ================= ARGMIN BLOCK =================
        const int bid = blockIdx.x;
        const int b = bid >> 5;           // 32 blocks per batch
        const int v0 = (bid & 31) * 256;

        // stage pts (2048 points of batch b) with exact sp
        #pragma unroll
        for (int i = 0; i < 4; ++i) {
            int p = t + i * 512;
            const float* g3 = graph_pos + ((size_t)b * NN + p) * 3;
            float px = g3[0], py = g3[1], pz = g3[2];
            float sp = __fadd_rn(__fadd_rn(__fmul_rn(px, px), __fmul_rn(py, py)),
                                 __fmul_rn(pz, pz));
            pts[p] = make_float4(px, py, pz, sp);
        }

        // vertex registers (Vt=4 per lane)
        float sv[4], tx[4], ty[4], tz[4];
        #pragma unroll
        for (int j = 0; j < 4; ++j) {
            int v = v0 + j * 64 + lane;
            const float* vp = verts + ((size_t)b * VV + v) * 3;
            float x = vp[0], y = vp[1], z = vp[2];
            sv[j] = __fadd_rn(__fadd_rn(__fmul_rn(x, x), __fmul_rn(y, y)),
                              __fmul_rn(z, z));
            tx[j] = x + x; ty[j] = y + y; tz[j] = z + z;   // exact 2x
        }
        __syncthreads();

        // scan: wave w covers point chunk [w*256, w*256+256)
        const float4* P = &pts[w * 256];
        float best[4] = {3.4e38f, 3.4e38f, 3.4e38f, 3.4e38f};
        int bi[4] = {0, 0, 0, 0};
        #pragma unroll 4
        for (int n = 0; n < 256; ++n) {
            float4 Q = P[n];   // ds_read_b128, same-addr broadcast (conflict-free)
            #pragma unroll
            for (int j = 0; j < 4; ++j) {
                float e2 = fmaf(tz[j], Q.z, fmaf(ty[j], Q.y, __fmul_rn(tx[j], Q.x)));
                float d2 = __fadd_rn(__fsub_rn(sv[j], e2), Q.w);
                if (d2 < best[j]) { best[j] = d2; bi[j] = n; }  // strict <: first idx
            }
        }

        __syncthreads();   // safe to alias u as merge scratch
        #pragma unroll
        for (int j = 0; j < 4; ++j) {
            u.m.sd[w * 256 + j * 64 + lane] = best[j];
            u.m.si[w * 256 + j * 64 + lane] = (unsigned short)(bi[j] + w * 256);
        }
        __syncthreads();

        if (t < 256) {
            float bb = u.m.sd[t];
            int   ii = u.m.si[t];
            #pragma unroll
            for (int c = 1; c < 8; ++c) {       // ascending chunks: first-index ties
                float d = u.m.sd[c * 256 + t];
                int   i = u.m.si[c * 256 + t];
                if (d < bb) { bb = d; ii = i; }
            }
            idx_out[(size_t)b * VV + v0 + t] = (unsigned short)ii;
        }
    } else {
        // ================= MLP BLOCK (32 rows) =================
        const int mb = blockIdx.x - 256;      // 0..511
        const int row0 = mb * 32;

        #pragma unroll
        for (int i = 0; i < 8; ++i) {
            int flat = i * 512 + t;           // 0..4095
            int r = flat >> 7;                // 0..31
            int k = flat & 127;
            u.selT[k * SEL_LD + r] = processed[(size_t)(row0 + r) * CC + k];
        }
        __syncthreads();

        const int g = t & 31;                 // col group: 4 cols
        const int rb = t >> 5;                // row group: 2 rows, 0..15
        const int c0 = g * 4;
        const int r0 = rb * 2;

        float acc[2][4] = {{0.f, 0.f, 0.f, 0.f}, {0.f, 0.f, 0.f, 0.f}};
        #pragma unroll 4
        for (int k = 0; k < CC; ++k) {
            float4 wv = *(const float4*)(W1 + k * CC + c0);
            float2 av = *(const float2*)(&u.selT[k * SEL_LD + r0]);
            acc[0][0] = fmaf(av.x, wv.x, acc[0][0]);
            acc[0][1] = fmaf(av.x, wv.y, acc[0][1]);
            acc[0][2] = fmaf(av.x, wv.z, acc[0][2]);
            acc[0][3] = fmaf(av.x, wv.w, acc[0][3]);
            acc[1][0] = fmaf(av.y, wv.x, acc[1][0]);
            acc[1][1] = fmaf(av.y, wv.y, acc[1][1]);
            acc[1][2] = fmaf(av.y, wv.z, acc[1][2]);
            acc[1][3] = fmaf(av.y, wv.w, acc[1][3]);
        }

        float4 b1v = *(const float4*)(b1 + c0);
        float4 w2v = *(const float4*)(W2 + c0);
        float bias2 = b2[0];

        #pragma unroll
        for (int i = 0; i < 2; ++i) {
            float h0 = acc[i][0] + b1v.x; h0 = h0 > 0.f ? h0 : 0.f;
            float h1 = acc[i][1] + b1v.y; h1 = h1 > 0.f ? h1 : 0.f;
            float h2 = acc[i][2] + b1v.z; h2 = h2 > 0.f ? h2 : 0.f;
            float h3 = acc[i][3] + b1v.w; h3 = h3 > 0.f ? h3 : 0.f;
            float p = fmaf(h0, w2v.x, fmaf(h1, w2v.y, fmaf(h2, w2v.z, h3 * w2v.w)));
            // reduce across the 32 col-lanes (xor offsets <32 stay in half-wave)
            #pragma unroll
            for (int off = 1; off < 32; off <<= 1) p += __shfl_xor(p, off, 64);
            if (g == 0) mlp_out[row0 + r0 + i] = p + bias2;
        }
    }
}

// K2: out[b,v] = mlp_out[b*NN + idx[b,v]]. mlp_out is 8 KB/batch -> L2 hot.
__global__ __launch_bounds__(256) void gather_kernel(
    const float* __restrict__ mlp_out, const unsigned short* __restrict__ idx,
    float* __restrict__ out)
{
    const int gid = blockIdx.x * 256 + threadIdx.x;   // 0..65535
    const int b = gid >> 13;                          // / VV
    out[gid] = mlp_out[b * NN + (int)idx[gid]];
}

extern "C" void kernel_launch(void* const* d_in, const int* in_sizes, int n_in,
                              void* d_out, int out_size, void* d_ws, size_t ws_size,
                              hipStream_t stream) {
    const float* verts     = (const float*)d_in[0];
    const float* graph_pos = (const float*)d_in[1];
    const float* processed = (const float*)d_in[2];
    const float* W1        = (const float*)d_in[3];
    const float* b1        = (const float*)d_in[4];
    const float* W2        = (const float*)d_in[5];
    const float* b2        = (const float*)d_in[6];
    float* out = (float*)d_out;

    float* mlp_out       = (float*)d_ws;                                 // 64 KB
    unsigned short* idxb = (unsigned short*)((char*)d_ws + BB * NN * 4); // 128 KB

    hipLaunchKernelGGL(argmin_mlp_kernel, dim3(768), dim3(512), 0, stream,
                       verts, graph_pos, processed, W1, b1, W2, b2,
                       mlp_out, idxb);
    hipLaunchKernelGGL(gather_kernel, dim3((BB * VV) / 256), dim3(256), 0, stream,
                       mlp_out, idxb, out);
}